// Round 1
// baseline (580.221 us; speedup 1.0000x reference)
//
#include <hip/hip_runtime.h>
#include <stdint.h>

typedef unsigned short u16;
typedef __bf16 bf16x8 __attribute__((ext_vector_type(8)));
typedef float f32x4 __attribute__((ext_vector_type(4)));
typedef unsigned short u16x8 __attribute__((ext_vector_type(8)));
typedef unsigned short u16x4 __attribute__((ext_vector_type(4)));

#define B_ROWS 4096
#define H_DIM  2048
#define K_DIM  4096   // concat K = IN + H
#define N_DIM  8192   // 4 gates * H, n = g*2048 + j

__device__ __forceinline__ u16 f2b(float f) {
  union { float f; unsigned int i; } v; v.f = f;
  unsigned int i = v.i;
  return (u16)((i + 0x7fffu + ((i >> 16) & 1u)) >> 16);  // RNE
}
__device__ __forceinline__ float b2f(u16 u) {
  union { unsigned int i; float f; } v; v.i = ((unsigned int)u) << 16; return v.f;
}
__device__ __forceinline__ float sigmoidf_(float x) { return 1.0f / (1.0f + __expf(-x)); }
__device__ __forceinline__ float tanhf_(float x)    { return 1.0f - 2.0f / (__expf(2.0f * x) + 1.0f); }

// async global->LDS, 16B per lane. LDS dest = wave-uniform base + lane*16.
__device__ __forceinline__ void glds16(const u16* g, u16* l) {
  __builtin_amdgcn_global_load_lds(
      (__attribute__((address_space(1))) void*)(g),
      (__attribute__((address_space(3))) void*)(l), 16, 0, 0);
}

struct WPtrs { const float* p[8]; };  // w_xi,w_xf,w_xo,w_xc,w_hi,w_hf,w_ho,w_hc (fp32)

// ---------------- prep: unchanged (proven) ----------------
__global__ __launch_bounds__(256) void prep_all(WPtrs wp,
                                                const float* __restrict__ X,
                                                const float* __restrict__ Hs,
                                                u16* __restrict__ Wt,
                                                u16* __restrict__ Abf) {
  __shared__ float tile[64][65];
  const int z = blockIdx.z;
  const int tid = threadIdx.x;
  if (z < 8) {
    const int s = z >> 2, g = z & 3;
    const float* __restrict__ w = wp.p[z];
    const int j0 = blockIdx.x * 64, k0 = blockIdx.y * 64;

    const int c4 = (tid & 15) * 4;
    const int r0 = tid >> 4;          // 0..15
#pragma unroll
    for (int it = 0; it < 4; ++it) {
      int r = r0 + it * 16;
      float4 v = *(const float4*)(w + (size_t)(k0 + r) * H_DIM + j0 + c4);
      tile[r][c4 + 0] = v.x;
      tile[r][c4 + 1] = v.y;
      tile[r][c4 + 2] = v.z;
      tile[r][c4 + 3] = v.w;
    }
    __syncthreads();

    const int cc = (tid & 7) * 8;     // kappa chunk
    const int jr0 = tid >> 3;         // 0..31
#pragma unroll
    for (int it = 0; it < 2; ++it) {
      int jr = jr0 + it * 32;
      u16x8 v;
#pragma unroll
      for (int i = 0; i < 8; ++i) v[i] = f2b(tile[cc + i][jr]);
      size_t orow = (size_t)(g * H_DIM + j0 + jr);
      *(u16x8*)(Wt + orow * K_DIM + (size_t)(s * H_DIM + k0 + cc)) = v;
    }
  } else {
    const int cid = (z - 8) * 1024 + blockIdx.y * 32 + blockIdx.x;   // 0..2047
#pragma unroll
    for (int t = 0; t < 4; ++t) {
      const size_t chunk = (size_t)cid * 1024 + t * 256 + tid;       // 8-elem chunk id
      const int b = (int)(chunk >> 9);
      const int c = ((int)chunk & 511) * 8;
      const float* src = (c < H_DIM) ? (X + (size_t)b * H_DIM + c)
                                     : (Hs + (size_t)b * H_DIM + (c - H_DIM));
      float4 v0 = *(const float4*)(src);
      float4 v1 = *(const float4*)(src + 4);
      u16x8 o;
      o[0] = f2b(v0.x); o[1] = f2b(v0.y); o[2] = f2b(v0.z); o[3] = f2b(v0.w);
      o[4] = f2b(v1.x); o[5] = f2b(v1.y); o[6] = f2b(v1.z); o[7] = f2b(v1.w);
      *(u16x8*)(Abf + chunk * 8) = o;
    }
  }
}

// ---------------- main GEMM: 256x256 tile, BK=32, 8 waves (2M x 4N), 512 thr.
// 4-deep LDS K-pipeline (slots T&3), staging 3 tiles ahead via global_load_lds,
// counted s_waitcnt vmcnt(8) at tile boundaries (never 0 in main loop),
// raw s_barrier (no vmcnt drain), s_setprio(1) around each 16-MFMA cluster.
// Swizzle (kc ^= (row>>1)&3), fragment layout, C/D mapping carried over from
// the proven 128^2 kernel unchanged.
//
// Soundness: boundary of tile T executes vmcnt(8) -> in-flight = {A,B}(T+2),
// {A,B}(T+3) only, so {A,B}(T+1) landed before any wave passes the barrier.
// Stage of tile T+3 targets slot (T+3)&3 whose previous occupant T-1 was fully
// read before the T-1 -> T boundary barrier (ds_reads complete before MFMA
// issue via lgkm deps). Tail peels vmcnt 8 -> 4 -> 0.
__global__ __launch_bounds__(512, 2) void gemm_gates(const u16* __restrict__ A,
                                                     const u16* __restrict__ Wt,
                                                     u16* __restrict__ gates) {
  __shared__ __align__(16) u16 sA[4 * 256 * 32];   // 4 slots x 16 KB
  __shared__ __align__(16) u16 sB[4 * 256 * 32];   // 4 slots x 16 KB  (total 128 KB)
  const int tid = threadIdx.x;
  const int wave = tid >> 6, lane = tid & 63;
  const int wm = wave >> 2, wn = wave & 3;         // 2 x 4 wave grid

  // XCD-aware bijective swizzle (512 % 8 == 0 -> simple form valid)
  const int wg = (blockIdx.x & 7) * 64 + (blockIdx.x >> 3);
  const int bm = wg & 15;      // 16 M-tiles (4096/256)
  const int bn = wg >> 4;      // 32 N-tiles (8192/256)

  // staging: per operand tile = 16 chunks of 1KB; wave w owns chunks {2w,2w+1}
  const int c0 = wave * 2;
  const int rs0 = c0 * 16 + (lane >> 2);
  const int rs1 = rs0 + 16;
  const int kc0 = (lane & 3) ^ ((rs0 >> 1) & 3);
  const int kc1 = (lane & 3) ^ ((rs1 >> 1) & 3);
  const size_t gA0 = (size_t)(bm * 256 + rs0) * K_DIM + kc0 * 8;
  const size_t gA1 = (size_t)(bm * 256 + rs1) * K_DIM + kc1 * 8;
  const size_t gB0 = (size_t)(bn * 256 + rs0) * K_DIM + kc0 * 8;
  const size_t gB1 = (size_t)(bn * 256 + rs1) * K_DIM + kc1 * 8;

  // fragment LDS offsets (u16 units) within one slot; q = k-chunk, XOR swizzle
  const int q = lane >> 4;
  int aOff[8], bOff[4];
#pragma unroll
  for (int i = 0; i < 8; ++i) {
    int ra = wm * 128 + i * 16 + (lane & 15);
    aOff[i] = ra * 32 + ((q ^ ((ra >> 1) & 3)) * 8);
  }
#pragma unroll
  for (int i = 0; i < 4; ++i) {
    int rb = wn * 64 + i * 16 + (lane & 15);
    bOff[i] = rb * 32 + ((q ^ ((rb >> 1) & 3)) * 8);
  }

  f32x4 acc[8][4] = {};
  const int NT = K_DIM / 32;   // 128 K-tiles

  // prologue: stage tiles 0,1,2 (12 loads/thread), wait tile 0 landed
#pragma unroll
  for (int t = 0; t < 3; ++t) {
    const size_t ko = (size_t)t * 32;
    u16* da = sA + t * 8192;
    u16* db = sB + t * 8192;
    glds16(A  + gA0 + ko, da + c0 * 512);
    glds16(A  + gA1 + ko, da + (c0 + 1) * 512);
    glds16(Wt + gB0 + ko, db + c0 * 512);
    glds16(Wt + gB1 + ko, db + (c0 + 1) * 512);
  }
  asm volatile("s_waitcnt vmcnt(8)" ::: "memory");
  __builtin_amdgcn_s_barrier();

  for (int T = 0; T < NT; ++T) {
    u16* sAs = sA + (T & 3) * 8192;
    u16* sBs = sB + (T & 3) * 8192;
    const int pf = T + 3;
    const bool dopf = pf < NT;
    const size_t ko = (size_t)pf * 32;
    u16* dA = sA + (pf & 3) * 8192;
    u16* dB = sB + (pf & 3) * 8192;

    // ---- phase 1: issue A(T+3) stage, read low-M frags + all B frags, MFMA
    if (dopf) {
      glds16(A + gA0 + ko, dA + c0 * 512);
      glds16(A + gA1 + ko, dA + (c0 + 1) * 512);
    }
    bf16x8 af[4], bf[4];
#pragma unroll
    for (int i = 0; i < 4; ++i) af[i] = *reinterpret_cast<const bf16x8*>(sAs + aOff[i]);
#pragma unroll
    for (int i = 0; i < 4; ++i) bf[i] = *reinterpret_cast<const bf16x8*>(sBs + bOff[i]);
    __builtin_amdgcn_s_barrier();
    __builtin_amdgcn_s_setprio(1);
#pragma unroll
    for (int mi = 0; mi < 4; ++mi)
#pragma unroll
      for (int ni = 0; ni < 4; ++ni)
        acc[mi][ni] = __builtin_amdgcn_mfma_f32_16x16x32_bf16(af[mi], bf[ni], acc[mi][ni], 0, 0, 0);
    __builtin_amdgcn_s_setprio(0);

    // ---- phase 2: issue B(T+3) stage, read high-M frags, MFMA
    if (dopf) {
      glds16(Wt + gB0 + ko, dB + c0 * 512);
      glds16(Wt + gB1 + ko, dB + (c0 + 1) * 512);
    }
    bf16x8 ag[4];
#pragma unroll
    for (int i = 0; i < 4; ++i) ag[i] = *reinterpret_cast<const bf16x8*>(sAs + aOff[4 + i]);
    __builtin_amdgcn_s_barrier();
    __builtin_amdgcn_s_setprio(1);
#pragma unroll
    for (int mi = 0; mi < 4; ++mi)
#pragma unroll
      for (int ni = 0; ni < 4; ++ni)
        acc[4 + mi][ni] = __builtin_amdgcn_mfma_f32_16x16x32_bf16(ag[mi], bf[ni], acc[4 + mi][ni], 0, 0, 0);
    __builtin_amdgcn_s_setprio(0);

    // ---- tile boundary: counted wait (T+1's 4 loads landed), then barrier
    if (T < NT - 3)       { asm volatile("s_waitcnt vmcnt(8)" ::: "memory"); }
    else if (T == NT - 3) { asm volatile("s_waitcnt vmcnt(4)" ::: "memory"); }
    else if (T == NT - 2) { asm volatile("s_waitcnt vmcnt(0)" ::: "memory"); }
    if (T < NT - 1) __builtin_amdgcn_s_barrier();
  }

  // C/D layout (m89-verified): col = lane&15, row = (lane>>4)*4 + reg
  const int rbase = bm * 256 + wm * 128 + (lane >> 4) * 4;
  const int cbase = bn * 256 + wn * 64 + (lane & 15);
#pragma unroll
  for (int mi = 0; mi < 8; ++mi) {
#pragma unroll
    for (int ni = 0; ni < 4; ++ni) {
      size_t base = (size_t)(rbase + mi * 16) * N_DIM + (size_t)(cbase + ni * 16);
#pragma unroll
      for (int r = 0; r < 4; ++r)
        gates[base + (size_t)r * N_DIM] = f2b(acc[mi][ni][r]);
    }
  }
}

// ---------------- epilogue: unchanged (proven) ----------------
__global__ __launch_bounds__(256) void lstm_epilogue(
    const u16* __restrict__ gates, const float* __restrict__ Cin,
    const float* __restrict__ Bi, const float* __restrict__ Bf,
    const float* __restrict__ Bo, const float* __restrict__ Bc,
    float* __restrict__ Out) {
  const int idx = blockIdx.x * 256 + threadIdx.x;   // 4 elems per thread
  const int b = idx >> 9;                           // 512 chunks of 4 per 2048-col row
  const int j = (idx & 511) * 4;
  const size_t gbase = (size_t)b * N_DIM + j;
  u16x4 iv = *(const u16x4*)(gates + gbase);
  u16x4 fv = *(const u16x4*)(gates + gbase + 2048);
  u16x4 ov = *(const u16x4*)(gates + gbase + 4096);
  u16x4 gv = *(const u16x4*)(gates + gbase + 6144);
  float4 cv  = *(const float4*)(Cin + (size_t)b * H_DIM + j);
  float4 biv = *(const float4*)(Bi + j);
  float4 bfv = *(const float4*)(Bf + j);
  float4 bov = *(const float4*)(Bo + j);
  float4 bcv = *(const float4*)(Bc + j);
  float ce[4] = {cv.x, cv.y, cv.z, cv.w};
  float bie[4] = {biv.x, biv.y, biv.z, biv.w};
  float bfe[4] = {bfv.x, bfv.y, bfv.z, bfv.w};
  float boe[4] = {bov.x, bov.y, bov.z, bov.w};
  float bce[4] = {bcv.x, bcv.y, bcv.z, bcv.w};
  float4 hv, ctv;
  float he[4], cte[4];
#pragma unroll
  for (int e = 0; e < 4; ++e) {
    float it = sigmoidf_(b2f(iv[e]) + bie[e]);
    float ft = sigmoidf_(b2f(fv[e]) + bfe[e]);
    float ot = sigmoidf_(b2f(ov[e]) + boe[e]);
    float gt = tanhf_(b2f(gv[e]) + bce[e]);
    float ct = ce[e] * ft + it * gt;
    he[e] = ot * tanhf_(ct);
    cte[e] = ct;
  }
  hv.x = he[0]; hv.y = he[1]; hv.z = he[2]; hv.w = he[3];
  ctv.x = cte[0]; ctv.y = cte[1]; ctv.z = cte[2]; ctv.w = cte[3];
  *(float4*)(Out + (size_t)b * H_DIM + j) = hv;                                       // h_t
  *(float4*)(Out + (size_t)B_ROWS * H_DIM + (size_t)b * H_DIM + j) = ctv;             // c_t
}

extern "C" void kernel_launch(void* const* d_in, const int* in_sizes, int n_in,
                              void* d_out, int out_size, void* d_ws, size_t ws_size,
                              hipStream_t stream) {
  const float* X   = (const float*)d_in[0];
  const float* Hs  = (const float*)d_in[1];
  const float* Cin = (const float*)d_in[2];
  WPtrs wp;
  for (int i = 0; i < 8; ++i) wp.p[i] = (const float*)d_in[3 + i];
  const float* Bi = (const float*)d_in[11];
  const float* Bf = (const float*)d_in[12];
  const float* Bo = (const float*)d_in[13];
  const float* Bc = (const float*)d_in[14];

  u16* Wt    = (u16*)d_ws;                        // [8192][4096] bf16 = 67.1 MB
  u16* Abf   = Wt + (size_t)N_DIM * K_DIM;        // [4096][4096] bf16 = 33.6 MB
  u16* gates = Abf + (size_t)B_ROWS * K_DIM;      // [4096][8192] bf16 = 67.1 MB
  float* Out = (float*)d_out;

  prep_all<<<dim3(32, 32, 10), 256, 0, stream>>>(wp, X, Hs, Wt, Abf);
  gemm_gates<<<16 * 32, 512, 0, stream>>>(Abf, Wt, gates);
  lstm_epilogue<<<(B_ROWS * H_DIM / 4) / 256, 256, 0, stream>>>(gates, Cin, Bi, Bf, Bo, Bc, Out);
}

// Round 2
// 519.234 us; speedup vs baseline: 1.1175x; 1.1175x over previous
//
#include <hip/hip_runtime.h>
#include <stdint.h>

typedef unsigned short u16;
typedef __bf16 bf16x8 __attribute__((ext_vector_type(8)));
typedef float f32x4 __attribute__((ext_vector_type(4)));
typedef unsigned short u16x8 __attribute__((ext_vector_type(8)));
typedef unsigned short u16x4 __attribute__((ext_vector_type(4)));

#define B_ROWS 4096
#define H_DIM  2048
#define K_DIM  4096   // concat K = IN + H
#define N_DIM  8192   // 4 gates * H, n = g*2048 + j

__device__ __forceinline__ u16 f2b(float f) {
  union { float f; unsigned int i; } v; v.f = f;
  unsigned int i = v.i;
  return (u16)((i + 0x7fffu + ((i >> 16) & 1u)) >> 16);  // RNE
}
__device__ __forceinline__ float b2f(u16 u) {
  union { unsigned int i; float f; } v; v.i = ((unsigned int)u) << 16; return v.f;
}
__device__ __forceinline__ float sigmoidf_(float x) { return 1.0f / (1.0f + __expf(-x)); }
__device__ __forceinline__ float tanhf_(float x)    { return 1.0f - 2.0f / (__expf(2.0f * x) + 1.0f); }

// async global->LDS, 16B per lane. LDS dest = wave-uniform base + lane*16.
__device__ __forceinline__ void glds16(const u16* g, u16* l) {
  __builtin_amdgcn_global_load_lds(
      (__attribute__((address_space(1))) void*)(g),
      (__attribute__((address_space(3))) void*)(l), 16, 0, 0);
}

// raw LDS byte offset of a generic pointer known to be in LDS
__device__ __forceinline__ uint32_t lds_off(const void* p) {
  return (uint32_t)(uintptr_t)(__attribute__((address_space(3))) const void*)p;
}

// inline-asm ds_read_b128: invisible to the compiler's waitcnt pass, so no
// conservative vmcnt(0) gets inserted between global_load_lds and LDS reads.
// MUST be followed (before any MFMA consumer) by s_waitcnt lgkmcnt(0) +
// sched_barrier(0) — rule #18.
__device__ __forceinline__ bf16x8 ds_read128(uint32_t byte_off) {
  bf16x8 r;
  asm volatile("ds_read_b128 %0, %1" : "=&v"(r) : "v"(byte_off));
  return r;
}
#define LGKM0   asm volatile("s_waitcnt lgkmcnt(0)" ::: "memory")
#define SCHED_FENCE __builtin_amdgcn_sched_barrier(0)

struct WPtrs { const float* p[8]; };  // w_xi,w_xf,w_xo,w_xc,w_hi,w_hf,w_ho,w_hc (fp32)

// ---------------- prep: unchanged (proven) ----------------
__global__ __launch_bounds__(256) void prep_all(WPtrs wp,
                                                const float* __restrict__ X,
                                                const float* __restrict__ Hs,
                                                u16* __restrict__ Wt,
                                                u16* __restrict__ Abf) {
  __shared__ float tile[64][65];
  const int z = blockIdx.z;
  const int tid = threadIdx.x;
  if (z < 8) {
    const int s = z >> 2, g = z & 3;
    const float* __restrict__ w = wp.p[z];
    const int j0 = blockIdx.x * 64, k0 = blockIdx.y * 64;

    const int c4 = (tid & 15) * 4;
    const int r0 = tid >> 4;          // 0..15
#pragma unroll
    for (int it = 0; it < 4; ++it) {
      int r = r0 + it * 16;
      float4 v = *(const float4*)(w + (size_t)(k0 + r) * H_DIM + j0 + c4);
      tile[r][c4 + 0] = v.x;
      tile[r][c4 + 1] = v.y;
      tile[r][c4 + 2] = v.z;
      tile[r][c4 + 3] = v.w;
    }
    __syncthreads();

    const int cc = (tid & 7) * 8;     // kappa chunk
    const int jr0 = tid >> 3;         // 0..31
#pragma unroll
    for (int it = 0; it < 2; ++it) {
      int jr = jr0 + it * 32;
      u16x8 v;
#pragma unroll
      for (int i = 0; i < 8; ++i) v[i] = f2b(tile[cc + i][jr]);
      size_t orow = (size_t)(g * H_DIM + j0 + jr);
      *(u16x8*)(Wt + orow * K_DIM + (size_t)(s * H_DIM + k0 + cc)) = v;
    }
  } else {
    const int cid = (z - 8) * 1024 + blockIdx.y * 32 + blockIdx.x;   // 0..2047
#pragma unroll
    for (int t = 0; t < 4; ++t) {
      const size_t chunk = (size_t)cid * 1024 + t * 256 + tid;       // 8-elem chunk id
      const int b = (int)(chunk >> 9);
      const int c = ((int)chunk & 511) * 8;
      const float* src = (c < H_DIM) ? (X + (size_t)b * H_DIM + c)
                                     : (Hs + (size_t)b * H_DIM + (c - H_DIM));
      float4 v0 = *(const float4*)(src);
      float4 v1 = *(const float4*)(src + 4);
      u16x8 o;
      o[0] = f2b(v0.x); o[1] = f2b(v0.y); o[2] = f2b(v0.z); o[3] = f2b(v0.w);
      o[4] = f2b(v1.x); o[5] = f2b(v1.y); o[6] = f2b(v1.z); o[7] = f2b(v1.w);
      *(u16x8*)(Abf + chunk * 8) = o;
    }
  }
}

// ---------------- main GEMM: 256x256 tile, BK=32, 8 waves (2M x 4N), 512 thr.
// 4-deep LDS K-pipeline (slots T&3), staging 3 tiles ahead via global_load_lds,
// counted s_waitcnt vmcnt(8) at tile boundaries (never 0 in main loop),
// raw s_barrier, s_setprio(1) around each 16-MFMA cluster.
// Round-2 change: fragment loads are inline-asm ds_read_b128 (waitcnt-pass
// invisible) + explicit lgkmcnt(0) + sched_barrier(0) before each MFMA
// cluster, so the compiler cannot insert a per-phase vmcnt(0) drain against
// the in-flight global_load_lds queue.
//
// Soundness: boundary of tile T executes vmcnt(8) -> in-flight = {A,B}(T+2),
// {A,B}(T+3) only, so {A,B}(T+1) landed before any wave crosses the barrier.
// Stage of tile T+3 targets slot (T+3)&3 whose previous occupant T-1 was fully
// read before the T-1 -> T boundary barrier (per-wave lgkmcnt(0) precedes its
// tile T-1 MFMAs; barrier makes that global). Tail peels vmcnt 8 -> 4 -> 0.
__global__ __launch_bounds__(512, 2) void gemm_gates(const u16* __restrict__ A,
                                                     const u16* __restrict__ Wt,
                                                     u16* __restrict__ gates) {
  __shared__ __align__(16) u16 sA[4 * 256 * 32];   // 4 slots x 16 KB
  __shared__ __align__(16) u16 sB[4 * 256 * 32];   // 4 slots x 16 KB  (total 128 KB)
  const int tid = threadIdx.x;
  const int wave = tid >> 6, lane = tid & 63;
  const int wm = wave >> 2, wn = wave & 3;         // 2 x 4 wave grid

  // XCD-aware bijective swizzle (512 % 8 == 0 -> simple form valid)
  const int wg = (blockIdx.x & 7) * 64 + (blockIdx.x >> 3);
  const int bm = wg & 15;      // 16 M-tiles (4096/256)
  const int bn = wg >> 4;      // 32 N-tiles (8192/256)

  // staging: per operand tile = 16 chunks of 1KB; wave w owns chunks {2w,2w+1}
  const int c0 = wave * 2;
  const int rs0 = c0 * 16 + (lane >> 2);
  const int rs1 = rs0 + 16;
  const int kc0 = (lane & 3) ^ ((rs0 >> 1) & 3);
  const int kc1 = (lane & 3) ^ ((rs1 >> 1) & 3);
  const size_t gA0 = (size_t)(bm * 256 + rs0) * K_DIM + kc0 * 8;
  const size_t gA1 = (size_t)(bm * 256 + rs1) * K_DIM + kc1 * 8;
  const size_t gB0 = (size_t)(bn * 256 + rs0) * K_DIM + kc0 * 8;
  const size_t gB1 = (size_t)(bn * 256 + rs1) * K_DIM + kc1 * 8;

  // fragment LDS byte offsets within one slot; q = k-chunk, XOR swizzle
  const int q = lane >> 4;
  uint32_t aOffB[8], bOffB[4];
#pragma unroll
  for (int i = 0; i < 8; ++i) {
    int ra = wm * 128 + i * 16 + (lane & 15);
    aOffB[i] = (uint32_t)(ra * 32 + ((q ^ ((ra >> 1) & 3)) * 8)) * 2u;
  }
#pragma unroll
  for (int i = 0; i < 4; ++i) {
    int rb = wn * 64 + i * 16 + (lane & 15);
    bOffB[i] = (uint32_t)(rb * 32 + ((q ^ ((rb >> 1) & 3)) * 8)) * 2u;
  }
  const uint32_t sAb = lds_off(sA);
  const uint32_t sBb = lds_off(sB);

  f32x4 acc[8][4] = {};
  const int NT = K_DIM / 32;   // 128 K-tiles

  // prologue: stage tiles 0,1,2 (12 loads/thread), wait tile 0 landed
#pragma unroll
  for (int t = 0; t < 3; ++t) {
    const size_t ko = (size_t)t * 32;
    u16* da = sA + t * 8192;
    u16* db = sB + t * 8192;
    glds16(A  + gA0 + ko, da + c0 * 512);
    glds16(A  + gA1 + ko, da + (c0 + 1) * 512);
    glds16(Wt + gB0 + ko, db + c0 * 512);
    glds16(Wt + gB1 + ko, db + (c0 + 1) * 512);
  }
  asm volatile("s_waitcnt vmcnt(8)" ::: "memory");
  __builtin_amdgcn_s_barrier();

  for (int T = 0; T < NT; ++T) {
    const uint32_t aSlot = sAb + (uint32_t)(T & 3) * 16384u;
    const uint32_t bSlot = sBb + (uint32_t)(T & 3) * 16384u;
    const int pf = T + 3;
    const bool dopf = pf < NT;
    const size_t ko = (size_t)pf * 32;
    u16* dA = sA + (pf & 3) * 8192;
    u16* dB = sB + (pf & 3) * 8192;

    // ---- phase 1: issue A(T+3) stage, asm-read low-M A frags + all B frags
    if (dopf) {
      glds16(A + gA0 + ko, dA + c0 * 512);
      glds16(A + gA1 + ko, dA + (c0 + 1) * 512);
    }
    bf16x8 af[4], bf[4];
#pragma unroll
    for (int i = 0; i < 4; ++i) af[i] = ds_read128(aSlot + aOffB[i]);
#pragma unroll
    for (int i = 0; i < 4; ++i) bf[i] = ds_read128(bSlot + bOffB[i]);
    __builtin_amdgcn_s_barrier();
    LGKM0;
    SCHED_FENCE;
    __builtin_amdgcn_s_setprio(1);
#pragma unroll
    for (int mi = 0; mi < 4; ++mi)
#pragma unroll
      for (int ni = 0; ni < 4; ++ni)
        acc[mi][ni] = __builtin_amdgcn_mfma_f32_16x16x32_bf16(af[mi], bf[ni], acc[mi][ni], 0, 0, 0);
    __builtin_amdgcn_s_setprio(0);

    // ---- phase 2: issue B(T+3) stage, asm-read high-M A frags
    if (dopf) {
      glds16(Wt + gB0 + ko, dB + c0 * 512);
      glds16(Wt + gB1 + ko, dB + (c0 + 1) * 512);
    }
    bf16x8 ag[4];
#pragma unroll
    for (int i = 0; i < 4; ++i) ag[i] = ds_read128(aSlot + aOffB[4 + i]);
    __builtin_amdgcn_s_barrier();
    LGKM0;
    SCHED_FENCE;
    __builtin_amdgcn_s_setprio(1);
#pragma unroll
    for (int mi = 0; mi < 4; ++mi)
#pragma unroll
      for (int ni = 0; ni < 4; ++ni)
        acc[4 + mi][ni] = __builtin_amdgcn_mfma_f32_16x16x32_bf16(ag[mi], bf[ni], acc[4 + mi][ni], 0, 0, 0);
    __builtin_amdgcn_s_setprio(0);

    // ---- tile boundary: counted wait (T+1's 4 loads landed), then barrier
    if (T < NT - 3)       { asm volatile("s_waitcnt vmcnt(8)" ::: "memory"); }
    else if (T == NT - 3) { asm volatile("s_waitcnt vmcnt(4)" ::: "memory"); }
    else if (T == NT - 2) { asm volatile("s_waitcnt vmcnt(0)" ::: "memory"); }
    if (T < NT - 1) __builtin_amdgcn_s_barrier();
  }

  // C/D layout (m89-verified): col = lane&15, row = (lane>>4)*4 + reg
  const int rbase = bm * 256 + wm * 128 + (lane >> 4) * 4;
  const int cbase = bn * 256 + wn * 64 + (lane & 15);
#pragma unroll
  for (int mi = 0; mi < 8; ++mi) {
#pragma unroll
    for (int ni = 0; ni < 4; ++ni) {
      size_t base = (size_t)(rbase + mi * 16) * N_DIM + (size_t)(cbase + ni * 16);
#pragma unroll
      for (int r = 0; r < 4; ++r)
        gates[base + (size_t)r * N_DIM] = f2b(acc[mi][ni][r]);
    }
  }
}

// ---------------- epilogue: unchanged (proven) ----------------
__global__ __launch_bounds__(256) void lstm_epilogue(
    const u16* __restrict__ gates, const float* __restrict__ Cin,
    const float* __restrict__ Bi, const float* __restrict__ Bf,
    const float* __restrict__ Bo, const float* __restrict__ Bc,
    float* __restrict__ Out) {
  const int idx = blockIdx.x * 256 + threadIdx.x;   // 4 elems per thread
  const int b = idx >> 9;                           // 512 chunks of 4 per 2048-col row
  const int j = (idx & 511) * 4;
  const size_t gbase = (size_t)b * N_DIM + j;
  u16x4 iv = *(const u16x4*)(gates + gbase);
  u16x4 fv = *(const u16x4*)(gates + gbase + 2048);
  u16x4 ov = *(const u16x4*)(gates + gbase + 4096);
  u16x4 gv = *(const u16x4*)(gates + gbase + 6144);
  float4 cv  = *(const float4*)(Cin + (size_t)b * H_DIM + j);
  float4 biv = *(const float4*)(Bi + j);
  float4 bfv = *(const float4*)(Bf + j);
  float4 bov = *(const float4*)(Bo + j);
  float4 bcv = *(const float4*)(Bc + j);
  float ce[4] = {cv.x, cv.y, cv.z, cv.w};
  float bie[4] = {biv.x, biv.y, biv.z, biv.w};
  float bfe[4] = {bfv.x, bfv.y, bfv.z, bfv.w};
  float boe[4] = {bov.x, bov.y, bov.z, bov.w};
  float bce[4] = {bcv.x, bcv.y, bcv.z, bcv.w};
  float4 hv, ctv;
  float he[4], cte[4];
#pragma unroll
  for (int e = 0; e < 4; ++e) {
    float it = sigmoidf_(b2f(iv[e]) + bie[e]);
    float ft = sigmoidf_(b2f(fv[e]) + bfe[e]);
    float ot = sigmoidf_(b2f(ov[e]) + boe[e]);
    float gt = tanhf_(b2f(gv[e]) + bce[e]);
    float ct = ce[e] * ft + it * gt;
    he[e] = ot * tanhf_(ct);
    cte[e] = ct;
  }
  hv.x = he[0]; hv.y = he[1]; hv.z = he[2]; hv.w = he[3];
  ctv.x = cte[0]; ctv.y = cte[1]; ctv.z = cte[2]; ctv.w = cte[3];
  *(float4*)(Out + (size_t)b * H_DIM + j) = hv;                                       // h_t
  *(float4*)(Out + (size_t)B_ROWS * H_DIM + (size_t)b * H_DIM + j) = ctv;             // c_t
}

extern "C" void kernel_launch(void* const* d_in, const int* in_sizes, int n_in,
                              void* d_out, int out_size, void* d_ws, size_t ws_size,
                              hipStream_t stream) {
  const float* X   = (const float*)d_in[0];
  const float* Hs  = (const float*)d_in[1];
  const float* Cin = (const float*)d_in[2];
  WPtrs wp;
  for (int i = 0; i < 8; ++i) wp.p[i] = (const float*)d_in[3 + i];
  const float* Bi = (const float*)d_in[11];
  const float* Bf = (const float*)d_in[12];
  const float* Bo = (const float*)d_in[13];
  const float* Bc = (const float*)d_in[14];

  u16* Wt    = (u16*)d_ws;                        // [8192][4096] bf16 = 67.1 MB
  u16* Abf   = Wt + (size_t)N_DIM * K_DIM;        // [4096][4096] bf16 = 33.6 MB
  u16* gates = Abf + (size_t)B_ROWS * K_DIM;      // [4096][8192] bf16 = 67.1 MB
  float* Out = (float*)d_out;

  prep_all<<<dim3(32, 32, 10), 256, 0, stream>>>(wp, X, Hs, Wt, Abf);
  gemm_gates<<<16 * 32, 512, 0, stream>>>(Abf, Wt, gates);
  lstm_epilogue<<<(B_ROWS * H_DIM / 4) / 256, 256, 0, stream>>>(gates, Cin, Bi, Bf, Bo, Bc, Out);
}

// Round 4
// 506.724 us; speedup vs baseline: 1.1450x; 1.0247x over previous
//
#include <hip/hip_runtime.h>
#include <stdint.h>

typedef unsigned short u16;
typedef __bf16 bf16x8 __attribute__((ext_vector_type(8)));
typedef float f32x4 __attribute__((ext_vector_type(4)));
typedef unsigned short u16x8 __attribute__((ext_vector_type(8)));
typedef unsigned short u16x4 __attribute__((ext_vector_type(4)));

#define B_ROWS 4096
#define H_DIM  2048
#define K_DIM  4096   // concat K = IN + H
#define N_DIM  8192   // 4 gates * H, n = g*2048 + j

__device__ __forceinline__ u16 f2b(float f) {
  union { float f; unsigned int i; } v; v.f = f;
  unsigned int i = v.i;
  return (u16)((i + 0x7fffu + ((i >> 16) & 1u)) >> 16);  // RNE
}
__device__ __forceinline__ float b2f(u16 u) {
  union { unsigned int i; float f; } v; v.i = ((unsigned int)u) << 16; return v.f;
}
__device__ __forceinline__ float sigmoidf_(float x) { return 1.0f / (1.0f + __expf(-x)); }
__device__ __forceinline__ float tanhf_(float x)    { return 1.0f - 2.0f / (__expf(2.0f * x) + 1.0f); }

// async global->LDS, 16B per lane. LDS dest = wave-uniform base + lane*16.
__device__ __forceinline__ void glds16(const u16* g, u16* l) {
  __builtin_amdgcn_global_load_lds(
      (__attribute__((address_space(1))) void*)(g),
      (__attribute__((address_space(3))) void*)(l), 16, 0, 0);
}

// raw LDS byte offset of a generic pointer known to be in LDS
__device__ __forceinline__ uint32_t lds_off(const void* p) {
  return (uint32_t)(uintptr_t)(__attribute__((address_space(3))) const void*)p;
}

// inline-asm ds_read_b128: invisible to the compiler's waitcnt pass (keeps it
// from inserting vmcnt(0) drains against in-flight global_load_lds), and lets
// us use COUNTED lgkmcnt. Every MFMA consumer must be preceded by the matching
// s_waitcnt + sched_barrier(0) — rule #18.
__device__ __forceinline__ bf16x8 ds_read128(uint32_t byte_off) {
  bf16x8 r;
  asm volatile("ds_read_b128 %0, %1" : "=&v"(r) : "v"(byte_off));
  return r;
}
// same, with +4096B immediate (high-half A rows: ra->ra+64 keeps the XOR
// swizzle term (ra>>1)&3 unchanged, so the byte offset is exactly +4096).
__device__ __forceinline__ bf16x8 ds_read128_hi(uint32_t byte_off) {
  bf16x8 r;
  asm volatile("ds_read_b128 %0, %1 offset:4096" : "=&v"(r) : "v"(byte_off));
  return r;
}
#define SCHED_FENCE __builtin_amdgcn_sched_barrier(0)

struct WPtrs { const float* p[8]; };  // w_xi,w_xf,w_xo,w_xc,w_hi,w_hf,w_ho,w_hc (fp32)

// ---------------- prep: unchanged (proven) ----------------
__global__ __launch_bounds__(256) void prep_all(WPtrs wp,
                                                const float* __restrict__ X,
                                                const float* __restrict__ Hs,
                                                u16* __restrict__ Wt,
                                                u16* __restrict__ Abf) {
  __shared__ float tile[64][65];
  const int z = blockIdx.z;
  const int tid = threadIdx.x;
  if (z < 8) {
    const int s = z >> 2, g = z & 3;
    const float* __restrict__ w = wp.p[z];
    const int j0 = blockIdx.x * 64, k0 = blockIdx.y * 64;

    const int c4 = (tid & 15) * 4;
    const int r0 = tid >> 4;          // 0..15
#pragma unroll
    for (int it = 0; it < 4; ++it) {
      int r = r0 + it * 16;
      float4 v = *(const float4*)(w + (size_t)(k0 + r) * H_DIM + j0 + c4);
      tile[r][c4 + 0] = v.x;
      tile[r][c4 + 1] = v.y;
      tile[r][c4 + 2] = v.z;
      tile[r][c4 + 3] = v.w;
    }
    __syncthreads();

    const int cc = (tid & 7) * 8;     // kappa chunk
    const int jr0 = tid >> 3;         // 0..31
#pragma unroll
    for (int it = 0; it < 2; ++it) {
      int jr = jr0 + it * 32;
      u16x8 v;
#pragma unroll
      for (int i = 0; i < 8; ++i) v[i] = f2b(tile[cc + i][jr]);
      size_t orow = (size_t)(g * H_DIM + j0 + jr);
      *(u16x8*)(Wt + orow * K_DIM + (size_t)(s * H_DIM + k0 + cc)) = v;
    }
  } else {
    const int cid = (z - 8) * 1024 + blockIdx.y * 32 + blockIdx.x;   // 0..2047
#pragma unroll
    for (int t = 0; t < 4; ++t) {
      const size_t chunk = (size_t)cid * 1024 + t * 256 + tid;       // 8-elem chunk id
      const int b = (int)(chunk >> 9);
      const int c = ((int)chunk & 511) * 8;
      const float* src = (c < H_DIM) ? (X + (size_t)b * H_DIM + c)
                                     : (Hs + (size_t)b * H_DIM + (c - H_DIM));
      float4 v0 = *(const float4*)(src);
      float4 v1 = *(const float4*)(src + 4);
      u16x8 o;
      o[0] = f2b(v0.x); o[1] = f2b(v0.y); o[2] = f2b(v0.z); o[3] = f2b(v0.w);
      o[4] = f2b(v1.x); o[5] = f2b(v1.y); o[6] = f2b(v1.z); o[7] = f2b(v1.w);
      *(u16x8*)(Abf + chunk * 8) = o;
    }
  }
}

// ---------------- main GEMM: 256x256 tile, BK=32, 8 waves (2M x 4N), 512 thr.
// Fragment-level software pipeline so ds_read overlaps MFMA.
// Per tile T (steady state):
//   (1) issue glds A(T+3)
//   (a) issue ds_read ag0-3(T)                       [4 reads, offset:4096]
//   (b) s_waitcnt lgkmcnt(4)  -> af/bf(T) (issued last iter) complete
//   (c) MFMA P0: af x bf_cur -> acc[0..3]            [ag reads in flight]
//       issue glds B(T+3)
//   (d) s_waitcnt vmcnt(8) lgkmcnt(0); s_barrier     [single sync per tile]
//   (e) issue ds_read af0-3(T+1), bf_next0-3(T+1)    [8 reads, slot validated]
//   (g) MFMA P1: ag x bf_cur -> acc[4..7]            [NO wait; 8 reads in flight]
// bf is live across both clusters while bf(T+1) streams in -> bf double-buffered
// (bfE/bfO), loop unrolled x2 for static buffer names (rule #20).
// Soundness: (b)/(d) lgkm waits mean every ds_read of tile T completes before
// the (d) barrier of tile T; glds(T+4) (same slot as T) issues only after that
// barrier. vmcnt(8) at (d): in-flight = (T+2),(T+3) only -> (T+1) landed before
// (e) reads it. DS ops retire in order -> counted lgkm waits are exact. Tail
// peels vmcnt 8 -> 4 -> 0; every wait is satisfiable (no hang path); barrier
// count is wave-uniform.
__global__ __launch_bounds__(512, 2) void gemm_gates(const u16* __restrict__ A,
                                                     const u16* __restrict__ Wt,
                                                     u16* __restrict__ gates) {
  __shared__ __align__(16) u16 sA[4 * 256 * 32];   // 4 slots x 16 KB
  __shared__ __align__(16) u16 sB[4 * 256 * 32];   // 4 slots x 16 KB  (total 128 KB)
  const int tid = threadIdx.x;
  const int wave = tid >> 6, lane = tid & 63;
  const int wm = wave >> 2, wn = wave & 3;         // 2 x 4 wave grid

  // XCD-aware bijective swizzle (512 % 8 == 0 -> simple form valid)
  const int wg = (blockIdx.x & 7) * 64 + (blockIdx.x >> 3);
  const int bm = wg & 15;      // 16 M-tiles (4096/256)
  const int bn = wg >> 4;      // 32 N-tiles (8192/256)

  // staging: per operand tile = 16 chunks of 1KB; wave w owns chunks {2w,2w+1}
  const int c0 = wave * 2;
  const int rs0 = c0 * 16 + (lane >> 2);
  const int rs1 = rs0 + 16;
  const int kc0 = (lane & 3) ^ ((rs0 >> 1) & 3);
  const int kc1 = (lane & 3) ^ ((rs1 >> 1) & 3);
  const size_t gA0 = (size_t)(bm * 256 + rs0) * K_DIM + kc0 * 8;
  const size_t gA1 = (size_t)(bm * 256 + rs1) * K_DIM + kc1 * 8;
  const size_t gB0 = (size_t)(bn * 256 + rs0) * K_DIM + kc0 * 8;
  const size_t gB1 = (size_t)(bn * 256 + rs1) * K_DIM + kc1 * 8;

  // fragment LDS byte offsets within one slot; q = k-chunk, XOR swizzle.
  // A high-half rows (i=4..7) are base+4096 handled via ds_read offset imm.
  const int q = lane >> 4;
  uint32_t aOffB[4], bOffB[4];
#pragma unroll
  for (int i = 0; i < 4; ++i) {
    int ra = wm * 128 + i * 16 + (lane & 15);
    aOffB[i] = (uint32_t)(ra * 32 + ((q ^ ((ra >> 1) & 3)) * 8)) * 2u;
  }
#pragma unroll
  for (int i = 0; i < 4; ++i) {
    int rb = wn * 64 + i * 16 + (lane & 15);
    bOffB[i] = (uint32_t)(rb * 32 + ((q ^ ((rb >> 1) & 3)) * 8)) * 2u;
  }
  const uint32_t sAb = lds_off(sA);
  const uint32_t sBb = lds_off(sB);

  f32x4 acc[8][4] = {};
  const int NT = K_DIM / 32;   // 128 K-tiles

  bf16x8 af[4], ag[4], bfE[4], bfO[4];

  // prologue: stage tiles 0,1,2; wait tile 0 landed; read P0(0) frags
#pragma unroll
  for (int t = 0; t < 3; ++t) {
    const size_t ko = (size_t)t * 32;
    u16* da = sA + t * 8192;
    u16* db = sB + t * 8192;
    glds16(A  + gA0 + ko, da + c0 * 512);
    glds16(A  + gA1 + ko, da + (c0 + 1) * 512);
    glds16(Wt + gB0 + ko, db + c0 * 512);
    glds16(Wt + gB1 + ko, db + (c0 + 1) * 512);
  }
  asm volatile("s_waitcnt vmcnt(8)" ::: "memory");
  __builtin_amdgcn_s_barrier();
  SCHED_FENCE;
#pragma unroll
  for (int i = 0; i < 4; ++i) af[i]  = ds_read128(sAb + aOffB[i]);
#pragma unroll
  for (int i = 0; i < 4; ++i) bfE[i] = ds_read128(sBb + bOffB[i]);

#define TILE_BODY(T, BFC, BFN)                                                 \
  {                                                                            \
    const int pf = (T) + 3;                                                    \
    const uint32_t aSlot = sAb + (uint32_t)((T) & 3) * 16384u;                 \
    const bool dopf = pf < NT;                                                 \
    const size_t ko = (size_t)pf * 32;                                         \
    if (dopf) {                                                                \
      u16* dA = sA + (pf & 3) * 8192;                                          \
      glds16(A + gA0 + ko, dA + c0 * 512);                                     \
      glds16(A + gA1 + ko, dA + (c0 + 1) * 512);                               \
    }                                                                          \
    /* (a) issue ag(T) — overlaps P0 MFMA */                                   \
    _Pragma("unroll")                                                          \
    for (int i = 0; i < 4; ++i) ag[i] = ds_read128_hi(aSlot + aOffB[i]);       \
    /* (b) af/bf(T) complete (oldest 8 of 12 outstanding; DS retires in order) */ \
    asm volatile("s_waitcnt lgkmcnt(4)" ::: "memory");                         \
    SCHED_FENCE;                                                               \
    __builtin_amdgcn_s_setprio(1);                                             \
    _Pragma("unroll")                                                          \
    for (int mi = 0; mi < 4; ++mi)                                             \
      _Pragma("unroll")                                                        \
      for (int ni = 0; ni < 4; ++ni)                                           \
        acc[mi][ni] = __builtin_amdgcn_mfma_f32_16x16x32_bf16(                 \
            af[mi], BFC[ni], acc[mi][ni], 0, 0, 0);                            \
    __builtin_amdgcn_s_setprio(0);                                             \
    if (dopf) {                                                                \
      u16* dB = sB + (pf & 3) * 8192;                                          \
      glds16(Wt + gB0 + ko, dB + c0 * 512);                                    \
      glds16(Wt + gB1 + ko, dB + (c0 + 1) * 512);                              \
    }                                                                          \
    /* (d) the single per-tile sync: ag done (slot safety) + (T+1) landed */   \
    if ((T) < NT - 3)       { asm volatile("s_waitcnt vmcnt(8) lgkmcnt(0)" ::: "memory"); } \
    else if ((T) == NT - 3) { asm volatile("s_waitcnt vmcnt(4) lgkmcnt(0)" ::: "memory"); } \
    else if ((T) == NT - 2) { asm volatile("s_waitcnt vmcnt(0) lgkmcnt(0)" ::: "memory"); } \
    else                    { asm volatile("s_waitcnt lgkmcnt(0)" ::: "memory"); }          \
    if ((T) < NT - 1) __builtin_amdgcn_s_barrier();                            \
    SCHED_FENCE;                                                               \
    /* (e) issue af/bf(T+1) — overlaps P1 MFMA */                              \
    if ((T) + 1 < NT) {                                                        \
      const uint32_t aN = sAb + (uint32_t)(((T) + 1) & 3) * 16384u;            \
      const uint32_t bN = sBb + (uint32_t)(((T) + 1) & 3) * 16384u;            \
      _Pragma("unroll")                                                        \
      for (int i = 0; i < 4; ++i) af[i]  = ds_read128(aN + aOffB[i]);          \
      _Pragma("unroll")                                                        \
      for (int i = 0; i < 4; ++i) BFN[i] = ds_read128(bN + bOffB[i]);          \
    }                                                                          \
    /* (g) P1 MFMA: no wait — operands guarded by (b) and (d) */               \
    __builtin_amdgcn_s_setprio(1);                                             \
    _Pragma("unroll")                                                          \
    for (int mi = 0; mi < 4; ++mi)                                             \
      _Pragma("unroll")                                                        \
      for (int ni = 0; ni < 4; ++ni)                                           \
        acc[4 + mi][ni] = __builtin_amdgcn_mfma_f32_16x16x32_bf16(             \
            ag[mi], BFC[ni], acc[4 + mi][ni], 0, 0, 0);                        \
    __builtin_amdgcn_s_setprio(0);                                             \
  }

  for (int T2 = 0; T2 < NT; T2 += 2) {
    TILE_BODY(T2,     bfE, bfO);
    TILE_BODY(T2 + 1, bfO, bfE);
  }
#undef TILE_BODY

  // C/D layout (m89-verified): col = lane&15, row = (lane>>4)*4 + reg
  const int rbase = bm * 256 + wm * 128 + (lane >> 4) * 4;
  const int cbase = bn * 256 + wn * 64 + (lane & 15);
#pragma unroll
  for (int mi = 0; mi < 8; ++mi) {
#pragma unroll
    for (int ni = 0; ni < 4; ++ni) {
      size_t base = (size_t)(rbase + mi * 16) * N_DIM + (size_t)(cbase + ni * 16);
#pragma unroll
      for (int r = 0; r < 4; ++r)
        gates[base + (size_t)r * N_DIM] = f2b(acc[mi][ni][r]);
    }
  }
}

// ---------------- epilogue: unchanged (proven) ----------------
__global__ __launch_bounds__(256) void lstm_epilogue(
    const u16* __restrict__ gates, const float* __restrict__ Cin,
    const float* __restrict__ Bi, const float* __restrict__ Bf,
    const float* __restrict__ Bo, const float* __restrict__ Bc,
    float* __restrict__ Out) {
  const int idx = blockIdx.x * 256 + threadIdx.x;   // 4 elems per thread
  const int b = idx >> 9;                           // 512 chunks of 4 per 2048-col row
  const int j = (idx & 511) * 4;
  const size_t gbase = (size_t)b * N_DIM + j;
  u16x4 iv = *(const u16x4*)(gates + gbase);
  u16x4 fv = *(const u16x4*)(gates + gbase + 2048);
  u16x4 ov = *(const u16x4*)(gates + gbase + 4096);
  u16x4 gv = *(const u16x4*)(gates + gbase + 6144);
  float4 cv  = *(const float4*)(Cin + (size_t)b * H_DIM + j);
  float4 biv = *(const float4*)(Bi + j);
  float4 bfv = *(const float4*)(Bf + j);
  float4 bov = *(const float4*)(Bo + j);
  float4 bcv = *(const float4*)(Bc + j);
  float ce[4] = {cv.x, cv.y, cv.z, cv.w};
  float bie[4] = {biv.x, biv.y, biv.z, biv.w};
  float bfe[4] = {bfv.x, bfv.y, bfv.z, bfv.w};
  float boe[4] = {bov.x, bov.y, bov.z, bov.w};
  float bce[4] = {bcv.x, bcv.y, bcv.z, bcv.w};
  float4 hv, ctv;
  float he[4], cte[4];
#pragma unroll
  for (int e = 0; e < 4; ++e) {
    float it = sigmoidf_(b2f(iv[e]) + bie[e]);
    float ft = sigmoidf_(b2f(fv[e]) + bfe[e]);
    float ot = sigmoidf_(b2f(ov[e]) + boe[e]);
    float gt = tanhf_(b2f(gv[e]) + bce[e]);
    float ct = ce[e] * ft + it * gt;
    he[e] = ot * tanhf_(ct);
    cte[e] = ct;
  }
  hv.x = he[0]; hv.y = he[1]; hv.z = he[2]; hv.w = he[3];
  ctv.x = cte[0]; ctv.y = cte[1]; ctv.z = cte[2]; ctv.w = cte[3];
  *(float4*)(Out + (size_t)b * H_DIM + j) = hv;                                       // h_t
  *(float4*)(Out + (size_t)B_ROWS * H_DIM + (size_t)b * H_DIM + j) = ctv;             // c_t
}

extern "C" void kernel_launch(void* const* d_in, const int* in_sizes, int n_in,
                              void* d_out, int out_size, void* d_ws, size_t ws_size,
                              hipStream_t stream) {
  const float* X   = (const float*)d_in[0];
  const float* Hs  = (const float*)d_in[1];
  const float* Cin = (const float*)d_in[2];
  WPtrs wp;
  for (int i = 0; i < 8; ++i) wp.p[i] = (const float*)d_in[3 + i];
  const float* Bi = (const float*)d_in[11];
  const float* Bf = (const float*)d_in[12];
  const float* Bo = (const float*)d_in[13];
  const float* Bc = (const float*)d_in[14];

  u16* Wt    = (u16*)d_ws;                        // [8192][4096] bf16 = 67.1 MB
  u16* Abf   = Wt + (size_t)N_DIM * K_DIM;        // [4096][4096] bf16 = 33.6 MB
  u16* gates = Abf + (size_t)B_ROWS * K_DIM;      // [4096][8192] bf16 = 67.1 MB
  float* Out = (float*)d_out;

  prep_all<<<dim3(32, 32, 10), 256, 0, stream>>>(wp, X, Hs, Wt, Abf);
  gemm_gates<<<16 * 32, 512, 0, stream>>>(Abf, Wt, gates);
  lstm_epilogue<<<(B_ROWS * H_DIM / 4) / 256, 256, 0, stream>>>(gates, Cin, Bi, Bf, Bo, Bc, Out);
}

// Round 5
// 493.509 us; speedup vs baseline: 1.1757x; 1.0268x over previous
//
#include <hip/hip_runtime.h>
#include <stdint.h>

typedef unsigned short u16;
typedef __bf16 bf16x8 __attribute__((ext_vector_type(8)));
typedef float f32x4 __attribute__((ext_vector_type(4)));
typedef unsigned short u16x8 __attribute__((ext_vector_type(8)));
typedef unsigned short u16x4 __attribute__((ext_vector_type(4)));

#define B_ROWS 4096
#define H_DIM  2048
#define K_DIM  4096   // concat K = IN + H
#define N_DIM  8192   // 4 gates * H (logical; no gates buffer anymore)

__device__ __forceinline__ u16 f2b(float f) {
  union { float f; unsigned int i; } v; v.f = f;
  unsigned int i = v.i;
  return (u16)((i + 0x7fffu + ((i >> 16) & 1u)) >> 16);  // RNE
}
__device__ __forceinline__ float b2f(u16 u) {
  union { unsigned int i; float f; } v; v.i = ((unsigned int)u) << 16; return v.f;
}
__device__ __forceinline__ float sigmoidf_(float x) { return 1.0f / (1.0f + __expf(-x)); }
__device__ __forceinline__ float tanhf_(float x)    { return 1.0f - 2.0f / (__expf(2.0f * x) + 1.0f); }

// async global->LDS, 16B per lane. LDS dest = wave-uniform base + lane*16.
__device__ __forceinline__ void glds16(const u16* g, u16* l) {
  __builtin_amdgcn_global_load_lds(
      (__attribute__((address_space(1))) void*)(g),
      (__attribute__((address_space(3))) void*)(l), 16, 0, 0);
}

// raw LDS byte offset of a generic pointer known to be in LDS
__device__ __forceinline__ uint32_t lds_off(const void* p) {
  return (uint32_t)(uintptr_t)(__attribute__((address_space(3))) const void*)p;
}

// inline-asm ds_read_b128: invisible to the compiler's waitcnt pass (keeps it
// from inserting vmcnt(0) drains against in-flight global_load_lds), and lets
// us use COUNTED lgkmcnt. Every MFMA consumer must be preceded by the matching
// s_waitcnt + sched_barrier(0) — rule #18.
__device__ __forceinline__ bf16x8 ds_read128(uint32_t byte_off) {
  bf16x8 r;
  asm volatile("ds_read_b128 %0, %1" : "=&v"(r) : "v"(byte_off));
  return r;
}
// same, with +4096B immediate (high-half A rows: ra->ra+64 keeps the XOR
// swizzle term (ra>>1)&3 unchanged, so the byte offset is exactly +4096).
__device__ __forceinline__ bf16x8 ds_read128_hi(uint32_t byte_off) {
  bf16x8 r;
  asm volatile("ds_read_b128 %0, %1 offset:4096" : "=&v"(r) : "v"(byte_off));
  return r;
}
#define SCHED_FENCE __builtin_amdgcn_sched_barrier(0)

struct WPtrs { const float* p[8]; };  // w_xi,w_xf,w_xo,w_xc,w_hi,w_hf,w_ho,w_hc (fp32)

// ---------------- prep: unchanged (proven) ----------------
__global__ __launch_bounds__(256) void prep_all(WPtrs wp,
                                                const float* __restrict__ X,
                                                const float* __restrict__ Hs,
                                                u16* __restrict__ Wt,
                                                u16* __restrict__ Abf) {
  __shared__ float tile[64][65];
  const int z = blockIdx.z;
  const int tid = threadIdx.x;
  if (z < 8) {
    const int s = z >> 2, g = z & 3;
    const float* __restrict__ w = wp.p[z];
    const int j0 = blockIdx.x * 64, k0 = blockIdx.y * 64;

    const int c4 = (tid & 15) * 4;
    const int r0 = tid >> 4;          // 0..15
#pragma unroll
    for (int it = 0; it < 4; ++it) {
      int r = r0 + it * 16;
      float4 v = *(const float4*)(w + (size_t)(k0 + r) * H_DIM + j0 + c4);
      tile[r][c4 + 0] = v.x;
      tile[r][c4 + 1] = v.y;
      tile[r][c4 + 2] = v.z;
      tile[r][c4 + 3] = v.w;
    }
    __syncthreads();

    const int cc = (tid & 7) * 8;     // kappa chunk
    const int jr0 = tid >> 3;         // 0..31
#pragma unroll
    for (int it = 0; it < 2; ++it) {
      int jr = jr0 + it * 32;
      u16x8 v;
#pragma unroll
      for (int i = 0; i < 8; ++i) v[i] = f2b(tile[cc + i][jr]);
      size_t orow = (size_t)(g * H_DIM + j0 + jr);
      *(u16x8*)(Wt + orow * K_DIM + (size_t)(s * H_DIM + k0 + cc)) = v;
    }
  } else {
    const int cid = (z - 8) * 1024 + blockIdx.y * 32 + blockIdx.x;   // 0..2047
#pragma unroll
    for (int t = 0; t < 4; ++t) {
      const size_t chunk = (size_t)cid * 1024 + t * 256 + tid;       // 8-elem chunk id
      const int b = (int)(chunk >> 9);
      const int c = ((int)chunk & 511) * 8;
      const float* src = (c < H_DIM) ? (X + (size_t)b * H_DIM + c)
                                     : (Hs + (size_t)b * H_DIM + (c - H_DIM));
      float4 v0 = *(const float4*)(src);
      float4 v1 = *(const float4*)(src + 4);
      u16x8 o;
      o[0] = f2b(v0.x); o[1] = f2b(v0.y); o[2] = f2b(v0.z); o[3] = f2b(v0.w);
      o[4] = f2b(v1.x); o[5] = f2b(v1.y); o[6] = f2b(v1.z); o[7] = f2b(v1.w);
      *(u16x8*)(Abf + chunk * 8) = o;
    }
  }
}

// ---------------- fused GEMM + LSTM epilogue ----------------
// 256x256 tile, BK=32, 8 waves (2M x 4N), 512 thr. K-loop schedule identical
// to the round-4 proven pipeline. N-RETILED: a block's 256 N-cols are now
// {4 gates x the SAME 64-wide j-window}: n = g*2048 + bj*64 + c. Only the
// GLOBAL B base rows change (n(rs) = (rs>>6)*2048 + bj*64 + (rs&63)); the LDS
// layout, XOR swizzle, fragment reads, and wave tiling are unchanged — wave
// (wm,wn) now owns gate wn for rows wm*128.., j-window bj*64..+64.
// After the K-loop: acc -> bf16 -> LDS (aliasing sA/sB; numerically identical
// to the old gates buffer), barrier, then the LSTM nonlinearity runs in-block
// with coalesced Cin/h/c traffic. No gates buffer, no third kernel.
#define GLS 260   // gl row-stride in u16: 8B-aligned (260*2%8==0), bank step 2
__global__ __launch_bounds__(512, 2) void gemm_fused(
    const u16* __restrict__ A, const u16* __restrict__ Wt,
    const float* __restrict__ Cin,
    const float* __restrict__ Bi, const float* __restrict__ Bff,
    const float* __restrict__ Bo, const float* __restrict__ Bc,
    float* __restrict__ Out) {
  // union: K-loop uses [0, 131072) bytes as sA/sB; epilogue reuses as gl
  // gl = u16[4 gates][64 j][GLS rows-padded] = 133120 B
  __shared__ __align__(16) u16 smem[4 * 64 * GLS];
  u16* sA = smem;                 // 4 slots x 16 KB
  u16* sB = smem + 4 * 8192;      // 4 slots x 16 KB
  const int tid = threadIdx.x;
  const int wave = tid >> 6, lane = tid & 63;
  const int wm = wave >> 2, wn = wave & 3;         // 2 x 4 wave grid; gate = wn

  // XCD-aware bijective swizzle (512 % 8 == 0 -> simple form valid)
  const int wg = (blockIdx.x & 7) * 64 + (blockIdx.x >> 3);
  const int bm = wg & 15;      // 16 M-tiles (4096/256)
  const int bj = wg >> 4;      // 32 j-windows (2048/64)

  // staging: per operand tile = 16 chunks of 1KB; wave w owns chunks {2w,2w+1}
  const int c0 = wave * 2;
  const int rs0 = c0 * 16 + (lane >> 2);           // LDS row 32w..32w+15
  const int rs1 = rs0 + 16;
  const int kc0 = (lane & 3) ^ ((rs0 >> 1) & 3);
  const int kc1 = (lane & 3) ^ ((rs1 >> 1) & 3);
  const size_t gA0 = (size_t)(bm * 256 + rs0) * K_DIM + kc0 * 8;
  const size_t gA1 = (size_t)(bm * 256 + rs1) * K_DIM + kc1 * 8;
  // B global rows: LDS row rs holds Wt row n(rs) = (rs>>6)*2048 + bj*64 + (rs&63)
  const int nB0 = (rs0 >> 6) * 2048 + bj * 64 + (rs0 & 63);
  const int nB1 = (rs1 >> 6) * 2048 + bj * 64 + (rs1 & 63);
  const size_t gB0 = (size_t)nB0 * K_DIM + kc0 * 8;
  const size_t gB1 = (size_t)nB1 * K_DIM + kc1 * 8;

  // fragment LDS byte offsets within one slot; q = k-chunk, XOR swizzle.
  // A high-half rows (i=4..7) are base+4096 handled via ds_read offset imm.
  const int q = lane >> 4;
  uint32_t aOffB[4], bOffB[4];
#pragma unroll
  for (int i = 0; i < 4; ++i) {
    int ra = wm * 128 + i * 16 + (lane & 15);
    aOffB[i] = (uint32_t)(ra * 32 + ((q ^ ((ra >> 1) & 3)) * 8)) * 2u;
  }
#pragma unroll
  for (int i = 0; i < 4; ++i) {
    int rb = wn * 64 + i * 16 + (lane & 15);
    bOffB[i] = (uint32_t)(rb * 32 + ((q ^ ((rb >> 1) & 3)) * 8)) * 2u;
  }
  const uint32_t sAb = lds_off(sA);
  const uint32_t sBb = lds_off(sB);

  f32x4 acc[8][4] = {};
  const int NT = K_DIM / 32;   // 128 K-tiles

  bf16x8 af[4], ag[4], bfE[4], bfO[4];

  // prologue: stage tiles 0,1,2; wait tile 0 landed; read P0(0) frags
#pragma unroll
  for (int t = 0; t < 3; ++t) {
    const size_t ko = (size_t)t * 32;
    u16* da = sA + t * 8192;
    u16* db = sB + t * 8192;
    glds16(A  + gA0 + ko, da + c0 * 512);
    glds16(A  + gA1 + ko, da + (c0 + 1) * 512);
    glds16(Wt + gB0 + ko, db + c0 * 512);
    glds16(Wt + gB1 + ko, db + (c0 + 1) * 512);
  }
  asm volatile("s_waitcnt vmcnt(8)" ::: "memory");
  __builtin_amdgcn_s_barrier();
  SCHED_FENCE;
#pragma unroll
  for (int i = 0; i < 4; ++i) af[i]  = ds_read128(sAb + aOffB[i]);
#pragma unroll
  for (int i = 0; i < 4; ++i) bfE[i] = ds_read128(sBb + bOffB[i]);

#define TILE_BODY(T, BFC, BFN)                                                 \
  {                                                                            \
    const int pf = (T) + 3;                                                    \
    const uint32_t aSlot = sAb + (uint32_t)((T) & 3) * 16384u;                 \
    const bool dopf = pf < NT;                                                 \
    const size_t ko = (size_t)pf * 32;                                         \
    if (dopf) {                                                                \
      u16* dA = sA + (pf & 3) * 8192;                                          \
      glds16(A + gA0 + ko, dA + c0 * 512);                                     \
      glds16(A + gA1 + ko, dA + (c0 + 1) * 512);                               \
    }                                                                          \
    /* (a) issue ag(T) — overlaps P0 MFMA */                                   \
    _Pragma("unroll")                                                          \
    for (int i = 0; i < 4; ++i) ag[i] = ds_read128_hi(aSlot + aOffB[i]);       \
    /* (b) af/bf(T) complete (oldest 8 of 12 outstanding; DS retires in order) */ \
    asm volatile("s_waitcnt lgkmcnt(4)" ::: "memory");                         \
    SCHED_FENCE;                                                               \
    __builtin_amdgcn_s_setprio(1);                                             \
    _Pragma("unroll")                                                          \
    for (int mi = 0; mi < 4; ++mi)                                             \
      _Pragma("unroll")                                                        \
      for (int ni = 0; ni < 4; ++ni)                                           \
        acc[mi][ni] = __builtin_amdgcn_mfma_f32_16x16x32_bf16(                 \
            af[mi], BFC[ni], acc[mi][ni], 0, 0, 0);                            \
    __builtin_amdgcn_s_setprio(0);                                             \
    if (dopf) {                                                                \
      u16* dB = sB + (pf & 3) * 8192;                                          \
      glds16(Wt + gB0 + ko, dB + c0 * 512);                                    \
      glds16(Wt + gB1 + ko, dB + (c0 + 1) * 512);                              \
    }                                                                          \
    /* (d) the single per-tile sync: ag done (slot safety) + (T+1) landed */   \
    if ((T) < NT - 3)       { asm volatile("s_waitcnt vmcnt(8) lgkmcnt(0)" ::: "memory"); } \
    else if ((T) == NT - 3) { asm volatile("s_waitcnt vmcnt(4) lgkmcnt(0)" ::: "memory"); } \
    else if ((T) == NT - 2) { asm volatile("s_waitcnt vmcnt(0) lgkmcnt(0)" ::: "memory"); } \
    else                    { asm volatile("s_waitcnt lgkmcnt(0)" ::: "memory"); }          \
    if ((T) < NT - 1) __builtin_amdgcn_s_barrier();                            \
    SCHED_FENCE;                                                               \
    /* (e) issue af/bf(T+1) — overlaps P1 MFMA */                              \
    if ((T) + 1 < NT) {                                                        \
      const uint32_t aN = sAb + (uint32_t)(((T) + 1) & 3) * 16384u;            \
      const uint32_t bN = sBb + (uint32_t)(((T) + 1) & 3) * 16384u;            \
      _Pragma("unroll")                                                        \
      for (int i = 0; i < 4; ++i) af[i]  = ds_read128(aN + aOffB[i]);          \
      _Pragma("unroll")                                                        \
      for (int i = 0; i < 4; ++i) BFN[i] = ds_read128(bN + bOffB[i]);          \
    }                                                                          \
    /* (g) P1 MFMA: no wait — operands guarded by (b) and (d) */               \
    __builtin_amdgcn_s_setprio(1);                                             \
    _Pragma("unroll")                                                          \
    for (int mi = 0; mi < 4; ++mi)                                             \
      _Pragma("unroll")                                                        \
      for (int ni = 0; ni < 4; ++ni)                                           \
        acc[4 + mi][ni] = __builtin_amdgcn_mfma_f32_16x16x32_bf16(             \
            ag[mi], BFC[ni], acc[4 + mi][ni], 0, 0, 0);                        \
    __builtin_amdgcn_s_setprio(0);                                             \
  }

  for (int T2 = 0; T2 < NT; T2 += 2) {
    TILE_BODY(T2,     bfE, bfO);
    TILE_BODY(T2 + 1, bfO, bfE);
  }
#undef TILE_BODY

  // ---- epilogue phase 1: acc -> bf16 -> gl[gate][j][row] (aliases sA/sB)
  // all waves done reading sA/sB for the final tile only after the barrier.
  __syncthreads();
  u16* gl = smem;
  {
    const int rowb = wm * 128 + (lane >> 4) * 4;   // + mi*16 + r
    const int jb   = lane & 15;                    // + ni*16
#pragma unroll
    for (int mi = 0; mi < 8; ++mi) {
#pragma unroll
      for (int ni = 0; ni < 4; ++ni) {
        const int row = rowb + mi * 16;
        const int j = jb + ni * 16;
        u16x4 o;
#pragma unroll
        for (int r = 0; r < 4; ++r) o[r] = f2b(acc[mi][ni][r]);
        *(u16x4*)(gl + (size_t)(wn * 64 + j) * GLS + row) = o;   // 8B-aligned
      }
    }
  }
  __syncthreads();

  // ---- epilogue phase 2: LSTM nonlinearity. lane = j, wave = row-group.
  {
    const int j = tid & 63;            // local j
    const int rg = tid >> 6;           // 0..7
    const int jg = bj * 64 + j;        // global column
    const float bi = Bi[jg], bf_ = Bff[jg], bo = Bo[jg], bc = Bc[jg];
    const size_t CH = (size_t)B_ROWS * H_DIM;
#pragma unroll
    for (int it = 0; it < 8; ++it) {
      const int row = rg * 4 + it * 32;            // local row, 4 consecutive
      u16x4 iv = *(const u16x4*)(gl + (size_t)(0 * 64 + j) * GLS + row);
      u16x4 fv = *(const u16x4*)(gl + (size_t)(1 * 64 + j) * GLS + row);
      u16x4 ov = *(const u16x4*)(gl + (size_t)(2 * 64 + j) * GLS + row);
      u16x4 gv = *(const u16x4*)(gl + (size_t)(3 * 64 + j) * GLS + row);
      const size_t grow = (size_t)(bm * 256 + row);
#pragma unroll
      for (int k = 0; k < 4; ++k) {
        const size_t gidx = (grow + k) * H_DIM + jg;
        float cold = Cin[gidx];
        float it_ = sigmoidf_(b2f(iv[k]) + bi);
        float ft_ = sigmoidf_(b2f(fv[k]) + bf_);
        float ot_ = sigmoidf_(b2f(ov[k]) + bo);
        float gt_ = tanhf_(b2f(gv[k]) + bc);
        float ct  = cold * ft_ + it_ * gt_;
        Out[gidx]      = ot_ * tanhf_(ct);   // h_t
        Out[CH + gidx] = ct;                 // c_t
      }
    }
  }
}

extern "C" void kernel_launch(void* const* d_in, const int* in_sizes, int n_in,
                              void* d_out, int out_size, void* d_ws, size_t ws_size,
                              hipStream_t stream) {
  const float* X   = (const float*)d_in[0];
  const float* Hs  = (const float*)d_in[1];
  const float* Cin = (const float*)d_in[2];
  WPtrs wp;
  for (int i = 0; i < 8; ++i) wp.p[i] = (const float*)d_in[3 + i];
  const float* Bi = (const float*)d_in[11];
  const float* Bf = (const float*)d_in[12];
  const float* Bo = (const float*)d_in[13];
  const float* Bc = (const float*)d_in[14];

  u16* Wt    = (u16*)d_ws;                        // [8192][4096] bf16 = 67.1 MB
  u16* Abf   = Wt + (size_t)N_DIM * K_DIM;        // [4096][4096] bf16 = 33.6 MB
  float* Out = (float*)d_out;

  prep_all<<<dim3(32, 32, 10), 256, 0, stream>>>(wp, X, Hs, Wt, Abf);
  gemm_fused<<<16 * 32, 512, 0, stream>>>(Abf, Wt, Cin, Bi, Bf, Bo, Bc, Out);
}